// Round 8
// baseline (5753.522 us; speedup 1.0000x reference)
//
#include <hip/hip_runtime.h>
#include <hip/hip_bf16.h>
#include <stdint.h>

// LSTM decoder: H=1024, B=4096, T=128, IN=1.
// R8 = R7 (BJ=64, BKK=64, conflict-free XOR swizzle, global_load_lds w16,
// XCD-grouped weights) + software-pipelined K-loop:
//   B tile double-buffered (2x32KB), A single (16KB) = 80 KB, 2 blocks/CU.
//   Staging loads issue at iter top / after mid-barrier and drain at iter end
//   (~900 cyc of compute cover) -> no stage->compute convoy.

#define HH 1024
#define BB 4096
#define TT 128

#define BM 128   // batch rows per block
#define BKK 64   // K tile
#define NKT (HH / BKK)  // 16

typedef __bf16 bf16;
typedef __bf16 v8bf __attribute__((ext_vector_type(8)));
typedef float f32x4 __attribute__((ext_vector_type(4)));

__device__ __forceinline__ float fast_sigmoid(float x) {
    return 1.0f / (1.0f + __expf(-x));
}
__device__ __forceinline__ float fast_tanh(float x) {
    return 1.0f - 2.0f / (__expf(2.0f * x) + 1.0f);
}

__device__ __forceinline__ void gload_lds16(const void* g, void* l) {
    __builtin_amdgcn_global_load_lds(
        (const __attribute__((address_space(1))) uint32_t*)(uintptr_t)g,
        (__attribute__((address_space(3))) uint32_t*)(uint32_t)(uintptr_t)l,
        16, 0, 0);
}

// ---- Prologue kernels ------------------------------------------------------

// Wr row layout: jb2*256 + g*64 + jj  <->  Whh row g*HH + jb2*64 + jj
__global__ void prep_weights(const float* __restrict__ Whh,
                             const float* __restrict__ bih,
                             const float* __restrict__ bhh,
                             bf16* __restrict__ Wr,
                             float* __restrict__ bias) {
    int idx = blockIdx.x * blockDim.x + threadIdx.x;
    if (idx < 4 * HH * HH) {
        int k   = idx & (HH - 1);
        int row = idx >> 10;
        int jb2 = row >> 8;
        int g   = (row >> 6) & 3;
        int jj  = row & 63;
        int srow = g * HH + jb2 * 64 + jj;
        Wr[idx] = (bf16)Whh[srow * HH + k];
    }
    if (idx < 4 * HH) bias[idx] = bih[idx] + bhh[idx];
}

__global__ void prep_h(const float* __restrict__ h0, bf16* __restrict__ hb) {
    int idx = blockIdx.x * blockDim.x + threadIdx.x;
    if (idx < BB * HH) hb[idx] = (bf16)h0[idx];
}

__global__ void prep_pred(float* __restrict__ predbuf, const float* __restrict__ b_out) {
    int idx = blockIdx.x * blockDim.x + threadIdx.x;
    if (idx < (TT + 1) * BB) predbuf[idx] = (idx < BB) ? 0.0f : b_out[0];
}

// ---- Per-step fused GEMM + cell update ------------------------------------
// 512 blocks = 16 jb2 x 32 bb. Block tile: 128 batch x 256 weight rows.

__global__ __launch_bounds__(256, 2)
void lstm_step(const bf16* __restrict__ hread, bf16* __restrict__ hwrite,
               const float* __restrict__ cin, float* __restrict__ cout,
               const bf16* __restrict__ Wr, const float* __restrict__ bias,
               const float* __restrict__ Wih, const float* __restrict__ Wout,
               const float* __restrict__ predbuf_r, float* __restrict__ predbuf_w) {
    // unpadded 128-B rows, XOR-swizzled: phys 16B-chunk = logical ^ (row&7)
    __shared__ bf16 As[BM][BKK];           // h tile: 128 x 64        (16 KB)
    __shared__ bf16 Bs[2][2 * BM][BKK];    // weights dbuf: 2x256x64  (64 KB)

    const int tid   = threadIdx.x;
    const int lane  = tid & 63;
    const int w     = tid >> 6;
    const int waveM = w >> 1, waveN = w & 1;
    const int quad  = lane >> 4, l15 = lane & 15;

    const int bid    = blockIdx.x;
    const int jb2    = (bid & 7) * 2 + ((bid >> 3) & 1); // 0..15, XCD-grouped
    const int blockB = (bid >> 4) * BM;                  // batch base

    f32x4 acc[4][8]; // [m-tile][gate*2 + j-half]
#pragma unroll
    for (int mi = 0; mi < 4; mi++)
#pragma unroll
        for (int nt = 0; nt < 8; nt++) acc[mi][nt] = (f32x4){0.f, 0.f, 0.f, 0.f};

    const bf16* Asrc = hread + (size_t)blockB * HH;
    const bf16* Bsrc = Wr + (size_t)jb2 * 256 * HH;

    const int r8  = lane >> 3;        // 0..7
    const int gc  = (lane & 7) ^ r8;  // swizzled global 16B-chunk for staging
    const int swr = l15 & 7;          // read-side swizzle key (row & 7)

#define STAGE_A(k0)                                                           \
    {                                                                         \
        _Pragma("unroll")                                                     \
        for (int c2 = 0; c2 < 4; c2++) {                                      \
            const int rowb = w * 32 + c2 * 8;                                 \
            gload_lds16(Asrc + (size_t)(rowb + r8) * HH + (k0) + gc * 8,      \
                        &As[rowb][0]);                                        \
        }                                                                     \
    }
#define STAGE_B(buf, k0)                                                      \
    {                                                                         \
        _Pragma("unroll")                                                     \
        for (int c2 = 0; c2 < 8; c2++) {                                      \
            const int rowb = w * 64 + c2 * 8;                                 \
            gload_lds16(Bsrc + (size_t)(rowb + r8) * HH + (k0) + gc * 8,      \
                        &Bs[buf][rowb][0]);                                   \
        }                                                                     \
    }

    STAGE_A(0);
    STAGE_B(0, 0);
    asm volatile("s_waitcnt vmcnt(0)" ::: "memory");
    __syncthreads();

#pragma unroll
    for (int kt = 0; kt < NKT; kt++) {
        // prefetch next B into the other buffer (free: its readers finished
        // before the previous end-barrier)
        if (kt + 1 < NKT) STAGE_B((kt + 1) & 1, (kt + 1) * BKK);

        // A fragments for both kk halves (must complete before A re-stage)
        v8bf a[2][4];
#pragma unroll
        for (int kk = 0; kk < 2; kk++)
#pragma unroll
            for (int mi = 0; mi < 4; mi++)
                a[kk][mi] = *(const v8bf*)
                    &As[waveM * 64 + mi * 16 + l15][((kk * 4 + quad) ^ swr) * 8];
        asm volatile("s_waitcnt lgkmcnt(0)" ::: "memory"); // own A-reads done
        asm volatile("s_barrier" ::: "memory");            // all waves' A-reads done
        if (kt + 1 < NKT) STAGE_A((kt + 1) * BKK);         // safe to overwrite As

        // B fragments + MFMA, per kk (keeps register peak < 256)
#pragma unroll
        for (int kk = 0; kk < 2; kk++) {
            v8bf b[8];
            const int pch = ((kk * 4 + quad) ^ swr) * 8;
#pragma unroll
            for (int g = 0; g < 4; g++)
#pragma unroll
                for (int jh = 0; jh < 2; jh++)
                    b[g * 2 + jh] = *(const v8bf*)
                        &Bs[kt & 1][g * 64 + waveN * 32 + jh * 16 + l15][pch];
#pragma unroll
            for (int mi = 0; mi < 4; mi++)
#pragma unroll
                for (int nt = 0; nt < 8; nt++)
                    acc[mi][nt] = __builtin_amdgcn_mfma_f32_16x16x32_bf16(
                        a[kk][mi], b[nt], acc[mi][nt], 0, 0, 0);
        }

        // drain this iter's staging (issued ~900 cyc ago) then sync
        asm volatile("s_waitcnt vmcnt(0)" ::: "memory");
        asm volatile("s_barrier" ::: "memory");
    }
#undef STAGE_A
#undef STAGE_B

    // Epilogue: acc[mi][g*2+jh][r] = gate g at (batch, j):
    //   batch = blockB + waveM*64 + mi*16 + quad*4 + r
    //   j     = jb2*64 + waveN*32 + jh*16 + l15
    float wihv[2][4], bsvv[2][4], wov[2];
#pragma unroll
    for (int jh = 0; jh < 2; jh++) {
        const int j = jb2 * 64 + waveN * 32 + jh * 16 + l15;
#pragma unroll
        for (int g = 0; g < 4; g++) {
            wihv[jh][g] = Wih[g * HH + j];
            bsvv[jh][g] = bias[g * HH + j];
        }
        wov[jh] = Wout[j];
    }

#pragma unroll
    for (int mi = 0; mi < 4; mi++) {
#pragma unroll
        for (int r = 0; r < 4; r++) {
            const int b = blockB + waveM * 64 + mi * 16 + quad * 4 + r;
            const float x = predbuf_r[b];  // pred_{t-1} (incl. b_out) or 0 at t=0
            float pacc = 0.0f;
#pragma unroll
            for (int jh = 0; jh < 2; jh++) {
                const int j = jb2 * 64 + waveN * 32 + jh * 16 + l15;
                const float gi = acc[mi][0 + jh][r] + x * wihv[jh][0] + bsvv[jh][0];
                const float gf = acc[mi][2 + jh][r] + x * wihv[jh][1] + bsvv[jh][1];
                const float gg = acc[mi][4 + jh][r] + x * wihv[jh][2] + bsvv[jh][2];
                const float go = acc[mi][6 + jh][r] + x * wihv[jh][3] + bsvv[jh][3];
                const float cn = fast_sigmoid(gf) * cin[(size_t)b * HH + j]
                               + fast_sigmoid(gi) * fast_tanh(gg);
                cout[(size_t)b * HH + j] = cn;
                const float hn = fast_sigmoid(go) * fast_tanh(cn);
                hwrite[(size_t)b * HH + j] = (bf16)hn;
                pacc += hn * wov[jh];
            }
            pacc += __shfl_xor(pacc, 1);
            pacc += __shfl_xor(pacc, 2);
            pacc += __shfl_xor(pacc, 4);
            pacc += __shfl_xor(pacc, 8);
            if (l15 == 0) atomicAdd(&predbuf_w[b], pacc);
        }
    }
}

// ---- Output transpose: out[b][t] = pred_t[b] ------------------------------

__global__ void write_out(const float* __restrict__ predbuf, float* __restrict__ out) {
    int idx = blockIdx.x * blockDim.x + threadIdx.x;
    if (idx < BB * TT) {
        int t = idx & (TT - 1);
        int b = idx >> 7;
        out[idx] = predbuf[(size_t)(t + 1) * BB + b];
    }
}

// ---- Host launch -----------------------------------------------------------

extern "C" void kernel_launch(void* const* d_in, const int* in_sizes, int n_in,
                              void* d_out, int out_size, void* d_ws, size_t ws_size,
                              hipStream_t stream) {
    const float* hidden = (const float*)d_in[0];
    const float* cell   = (const float*)d_in[1];
    const float* Wih    = (const float*)d_in[2];
    const float* Whh    = (const float*)d_in[3];
    const float* bih    = (const float*)d_in[4];
    const float* bhh    = (const float*)d_in[5];
    const float* Wout   = (const float*)d_in[6];
    const float* bout   = (const float*)d_in[7];
    float* out = (float*)d_out;

    char* ws = (char*)d_ws;
    bf16* Wr = (bf16*)ws;        ws += (size_t)4 * HH * HH * 2;   // 8 MB
    bf16* hb0 = (bf16*)ws;       ws += (size_t)BB * HH * 2;       // 8 MB
    bf16* hb1 = (bf16*)ws;       ws += (size_t)BB * HH * 2;       // 8 MB
    float* cbuf = (float*)ws;    ws += (size_t)BB * HH * 4;       // 16 MB
    float* bias = (float*)ws;    ws += (size_t)4 * HH * 4;        // 16 KB
    float* predbuf = (float*)ws; ws += (size_t)(TT + 1) * BB * 4; // 2.1 MB

    prep_weights<<<(4 * HH * HH + 255) / 256, 256, 0, stream>>>(Whh, bih, bhh, Wr, bias);
    prep_h<<<(BB * HH + 255) / 256, 256, 0, stream>>>(hidden, hb0);
    prep_pred<<<((TT + 1) * BB + 255) / 256, 256, 0, stream>>>(predbuf, bout);

    bf16* hb[2] = {hb0, hb1};
    for (int t = 0; t < TT; t++) {
        const bf16* hr = hb[t & 1];
        bf16* hw = hb[(t + 1) & 1];
        const float* ci = (t == 0) ? cell : cbuf;
        lstm_step<<<16 * (BB / BM), 256, 0, stream>>>(
            hr, hw, ci, cbuf, Wr, bias, Wih, Wout,
            predbuf + (size_t)t * BB, predbuf + (size_t)(t + 1) * BB);
    }

    write_out<<<(BB * TT + 255) / 256, 256, 0, stream>>>(predbuf, out);
}